// Round 16
// baseline (270.529 us; speedup 1.0000x reference)
//
#include <hip/hip_runtime.h>

#pragma clang fp contract(off)

#define BATCH 16
#define NPTS  4096
#define KNN   32
#define CH    30
#define NW    8                 // waves per block = chunk count
#define CHUNK (NPTS / NW)       // 512 candidates per wave
#define QPB   128               // queries per block (2 per lane: A=l, B=l+64)
#define FD    28                // FIFO capacity per (region,query); slot FD = trash
#define FSTR  29                // u16 slots per query column

#define INF_F __builtin_inff()

typedef __attribute__((ext_vector_type(2))) float f32x2;

__device__ __forceinline__ unsigned enc_f32(float f) {
    unsigned u = __float_as_uint(f);
    return (u & 0x80000000u) ? ~u : (u | 0x80000000u);
}
__device__ __forceinline__ float dec_f32(unsigned e) {
    unsigned u = (e & 0x80000000u) ? (e & 0x7FFFFFFFu) : ~e;
    return __uint_as_float(u);
}

__device__ __forceinline__ float med3f(float a, float b, float c) {
#if __has_builtin(__builtin_amdgcn_fmed3f)
    return __builtin_amdgcn_fmed3f(a, b, c);
#else
    float r;
    asm("v_med3_f32 %0, %1, %2, %3" : "=v"(r) : "v"(a), "v"(b), "v"(c));
    return r;
#endif
}

// Scalar difference-form squared distance (phase 3; the reference metric).
__device__ __forceinline__ float dist3d(float qx, float qy, float qz,
                                        float px, float py, float pz) {
    float r0 = px - qx, r1 = py - qy, r2 = pz - qz;
    return __builtin_fmaf(r0, r0, __builtin_fmaf(r1, r1, r2 * r2));
}

// Packed 2-query distance: scalar candidate splats into both slots (op_sel),
// per-slot operation sequence IDENTICAL to dist3d -> bit-identical per slot.
__device__ __forceinline__ f32x2 dist2q(f32x2 qxx, f32x2 qyy, f32x2 qzz,
                                        float px, float py, float pz) {
    f32x2 r0 = px - qxx, r1 = py - qyy, r2 = pz - qzz;
    return __builtin_elementwise_fma(r0, r0,
           __builtin_elementwise_fma(r1, r1, r2 * r2));
}

__global__ void init_pool_kernel(unsigned* __restrict__ pool) {
    int i = blockIdx.x * blockDim.x + threadIdx.x;
    if (i < BATCH * CH) pool[i] = 0u;   // 0 is below every encoded finite float
}

// 512 thr = 8 waves, 128 queries/block (2 per lane, packed f32 math).
// Wave w scans chunk [w*512, w*512+512); phase 3 is wave-parallel per query
// (wave w handles queries w*16..w*16+15), verbatim from the r14 lineage.
__launch_bounds__(512, 4)
__global__ void knn_kernel(const float* __restrict__ x,
                           unsigned* __restrict__ pool) {
    __shared__ unsigned short fifo[NW * QPB * FSTR];  // 59392 B [r][query][slot]
    __shared__ float t8[NW * QPB];                    // 4096 B chunk-4th stash
    __shared__ unsigned char cbs[NW * QPB];           // 1024 B survivor counts
    __shared__ unsigned pool_lds[CH];                 // 120 B block max-pool

    const int b   = blockIdx.x >> 5;              // 32 query-pair-groups/batch
    const int g   = blockIdx.x & 31;
    const int tid = threadIdx.x;
    const int w   = tid >> 6;                     // wave id = chunk id (0..7)
    const int l   = tid & 63;
    const float* __restrict__ xb = x + (size_t)b * NPTS * 3;

    if (tid < CH) pool_lds[tid] = 0u;

    const int qA = g * QPB + l;                   // query A (column l)
    const int qB = qA + 64;                       // query B (column 64+l)
    const f32x2 qxx = { xb[qA * 3 + 0], xb[qB * 3 + 0] };
    const f32x2 qyy = { xb[qA * 3 + 1], xb[qB * 3 + 1] };
    const f32x2 qzz = { xb[qA * 3 + 2], xb[qB * 3 + 2] };

    const int wu = __builtin_amdgcn_readfirstlane(w);
    const float* __restrict__ cw = xb + (size_t)wu * (CHUNK * 3);

    // ---- Pass 1: per-query top-4 of my chunk (named scalars, packed dist).
    // Union of 8 chunk-top-4s = 32 distinct points => t_cap >= true d32.
    float A0 = INF_F, A1 = INF_F, A2 = INF_F, A3 = INF_F;
    float C0 = INF_F, C1 = INF_F, C2 = INF_F, C3 = INF_F;
#pragma unroll 4
    for (int m = 0; m < CHUNK; ++m) {
        float px = cw[3 * m + 0], py = cw[3 * m + 1], pz = cw[3 * m + 2];
        f32x2 dd = dist2q(qxx, qyy, qzz, px, py, pz);
        float dA = dd[0], dB = dd[1];
        A3 = med3f(A2, A3, dA); A2 = med3f(A1, A2, dA);
        A1 = med3f(A0, A1, dA); A0 = fminf(A0, dA);
        C3 = med3f(C2, C3, dB); C2 = med3f(C1, C2, dB);
        C1 = med3f(C0, C1, dB); C0 = fminf(C0, dB);
    }
    t8[w * QPB + l]      = A3;
    t8[w * QPB + 64 + l] = C3;
    __syncthreads();
    float tcA = t8[l], tcB = t8[64 + l];
#pragma unroll
    for (int ww = 1; ww < NW; ++ww) {
        tcA = fmaxf(tcA, t8[ww * QPB + l]);
        tcB = fmaxf(tcB, t8[ww * QPB + 64 + l]);
    }

    // ---- Pass 2: branchless collect of global u16 indices with d <= t_cap.
    unsigned short* __restrict__ fA = fifo + (w * QPB + l) * FSTR;
    unsigned short* __restrict__ fB = fifo + (w * QPB + 64 + l) * FSTR;
    int cntA = 0, cntB = 0;
#pragma unroll 4
    for (int m = 0; m < CHUNK; ++m) {
        float px = cw[3 * m + 0], py = cw[3 * m + 1], pz = cw[3 * m + 2];
        f32x2 dd = dist2q(qxx, qyy, qzz, px, py, pz);
        unsigned short gi = (unsigned short)(wu * CHUNK + m);
        { bool t = (dd[0] <= tcA) && (cntA < FD); fA[t ? cntA : FD] = gi; cntA += t; }
        { bool t = (dd[1] <= tcB) && (cntB < FD); fB[t ? cntB : FD] = gi; cntB += t; }
    }
    cbs[w * QPB + l]      = (unsigned char)cntA;
    cbs[w * QPB + 64 + l] = (unsigned char)cntB;
    __syncthreads();

    // ---- Phase 3: wave w processes queries j = w*16 .. w*16+15. ----
#define BSTEP(V, K, J)                                            \
    {                                                             \
        float pv_ = __shfl_xor((V), (J), 64);                     \
        bool km_ = (((l & (K)) == 0) == ((l & (J)) == 0));        \
        (V) = km_ ? fminf((V), pv_) : fmaxf((V), pv_);            \
    }
#define SORT64(V)                                                      \
    BSTEP(V, 2, 1)                                                     \
    BSTEP(V, 4, 2)  BSTEP(V, 4, 1)                                     \
    BSTEP(V, 8, 4)  BSTEP(V, 8, 2)  BSTEP(V, 8, 1)                     \
    BSTEP(V, 16, 8) BSTEP(V, 16, 4) BSTEP(V, 16, 2) BSTEP(V, 16, 1)    \
    BSTEP(V, 32,16) BSTEP(V, 32, 8) BSTEP(V, 32, 4) BSTEP(V, 32, 2) BSTEP(V, 32, 1) \
    BSTEP(V, 64,32) BSTEP(V, 64,16) BSTEP(V, 64, 8) BSTEP(V, 64, 4) BSTEP(V, 64, 2) BSTEP(V, 64, 1)
#define CLEAN64(V) \
    BSTEP(V, 64,32) BSTEP(V, 64,16) BSTEP(V, 64, 8) BSTEP(V, 64, 4) BSTEP(V, 64, 2) BSTEP(V, 64, 1)

#define SURV_LOAD(OFF, DOR, PX, PY, PZ)                                       \
    {                                                                         \
        int o_ = (OFF) + l;                                                   \
        int base_ = 0;                                                        \
        base_ = (o_ >= P1) ? P1 : base_;  base_ = (o_ >= P2) ? P2 : base_;    \
        base_ = (o_ >= P3) ? P3 : base_;  base_ = (o_ >= P4) ? P4 : base_;    \
        base_ = (o_ >= P5) ? P5 : base_;  base_ = (o_ >= P6) ? P6 : base_;    \
        base_ = (o_ >= P7) ? P7 : base_;                                      \
        int reg_ = (o_>=P1)+(o_>=P2)+(o_>=P3)+(o_>=P4)+(o_>=P5)+(o_>=P6)+(o_>=P7); \
        int s_ = o_ - base_;  s_ = (s_ > FD) ? FD : s_;                       \
        int idx_ = (int)fifo[(reg_ * QPB + j) * FSTR + s_];                   \
        const float* pp_ = xb + 3 * idx_;                                     \
        (PX) = pp_[0]; (PY) = pp_[1]; (PZ) = pp_[2];                          \
        float d_ = dist3d(qjx, qjy, qjz, (PX), (PY), (PZ));                   \
        (DOR) = (o_ < S) ? d_ : INF_F;                                        \
    }

#define RSUM(V) { _Pragma("unroll") for (int o_ = 32; o_ >= 1; o_ >>= 1) (V) += __shfl_xor((V), o_, 64); }
#define RMAXW(V) { _Pragma("unroll") for (int o_ = 32; o_ >= 1; o_ >>= 1) (V) = fmaxf((V), __shfl_xor((V), o_, 64)); }
#define RMINW(V) { _Pragma("unroll") for (int o_ = 32; o_ >= 1; o_ >>= 1) (V) = fminf((V), __shfl_xor((V), o_, 64)); }

#pragma unroll 1
    for (int jj = 0; jj < 16; ++jj) {
        const int j  = w * 16 + jj;
        const int qj = g * QPB + j;
        const float qjx = xb[qj * 3 + 0], qjy = xb[qj * 3 + 1], qjz = xb[qj * 3 + 2];

        const int c0 = cbs[0 * QPB + j], c1 = cbs[1 * QPB + j],
                  c2 = cbs[2 * QPB + j], c3 = cbs[3 * QPB + j],
                  c4 = cbs[4 * QPB + j], c5 = cbs[5 * QPB + j],
                  c6 = cbs[6 * QPB + j], c7 = cbs[7 * QPB + j];
        const int P1 = c0,      P2 = P1 + c1, P3 = P2 + c2, P4 = P3 + c3,
                  P5 = P4 + c4, P6 = P5 + c5, P7 = P6 + c6, S  = P7 + c7;

        float px1, py1, pz1, dor1;
        SURV_LOAD(0, dor1, px1, py1, pz1);
        float v = dor1;
        SORT64(v)

        float thr;
        float px2 = 0.f, py2 = 0.f, pz2 = 0.f, dor2 = INF_F;
        const bool two = (S > 64);                 // wave-uniform
        if (two) {
            SURV_LOAD(64, dor2, px2, py2, pz2);
            float v2 = dor2;
            SORT64(v2)
            float rb = __shfl(v2, 63 - l, 64);     // reversed batch-2
            float lo = fminf(v, rb);               // bitonic lowest-64
            CLEAN64(lo)
            thr = __shfl(lo, 31, 64);
        } else {
            thr = __shfl(v, 31, 64);               // 32nd smallest
        }

        const unsigned long long blt = (l == 0) ? 0ull : (~0ull >> (64 - l));
        unsigned long long meq1 = __ballot(dor1 == thr);
        int clt = __popcll(__ballot(dor1 < thr));
        int neq1 = __popcll(meq1);
        int rank1 = __popcll(meq1 & blt);
        int rank2 = 0;
        if (two) {
            unsigned long long meq2 = __ballot(dor2 == thr);
            clt += __popcll(__ballot(dor2 < thr));
            rank2 = neq1 + __popcll(meq2 & blt);
        }
        const int need = KNN - clt;
        const bool take1 = (dor1 < thr) || ((dor1 == thr) && (rank1 < need));
        const bool take2 = two && ((dor2 < thr) || ((dor2 == thr) && (rank2 < need)));

        float r10 = px1 - qjx, r11 = py1 - qjy, r12 = pz1 - qjz;
        float r20 = px2 - qjx, r21 = py2 - qjy, r22 = pz2 - qjz;
        float s0 = (take1 ? r10 : 0.f) + (take2 ? r20 : 0.f);
        float s1 = (take1 ? r11 : 0.f) + (take2 ? r21 : 0.f);
        float s2 = (take1 ? r12 : 0.f) + (take2 ? r22 : 0.f);
        float ss0 = (take1 ? r10 * r10 : 0.f) + (take2 ? r20 * r20 : 0.f);
        float ss1 = (take1 ? r11 * r11 : 0.f) + (take2 ? r21 * r21 : 0.f);
        float ss2 = (take1 ? r12 * r12 : 0.f) + (take2 ? r22 * r22 : 0.f);
        float mx0 = fmaxf(take1 ? r10 : -INF_F, take2 ? r20 : -INF_F);
        float mx1 = fmaxf(take1 ? r11 : -INF_F, take2 ? r21 : -INF_F);
        float mx2 = fmaxf(take1 ? r12 : -INF_F, take2 ? r22 : -INF_F);
        float mn0 = fminf(take1 ? r10 : INF_F, take2 ? r20 : INF_F);
        float mn1 = fminf(take1 ? r11 : INF_F, take2 ? r21 : INF_F);
        float mn2 = fminf(take1 ? r12 : INF_F, take2 ? r22 : INF_F);

        RSUM(s0)  RSUM(s1)  RSUM(s2)
        RSUM(ss0) RSUM(ss1) RSUM(ss2)
        RMAXW(mx0) RMAXW(mx1) RMAXW(mx2)
        RMINW(mn0) RMINW(mn1) RMINW(mn2)

        const float invk = 1.0f / (float)KNN;
        float mu0 = s0 * invk, mu1 = s1 * invk, mu2 = s2 * invk;
        float ex0 = ss0 * invk, ex1 = ss1 * invk, ex2 = ss2 * invk;
        float st0 = sqrtf(fmaxf(ex0 - mu0 * mu0, 0.f));
        float st1 = sqrtf(fmaxf(ex1 - mu1 * mu1, 0.f));
        float st2 = sqrtf(fmaxf(ex2 - mu2 * mu2, 0.f));
        float nrm = sqrtf(mu0 * mu0 + mu1 * mu1 + mu2 * mu2) + 1e-8f;
        float u0 = mu0 / nrm, u1 = mu1 / nrm, u2 = mu2 / nrm;
        float cr0 = qjy * u2 - qjz * u1;
        float cr1 = qjz * u0 - qjx * u2;
        float cr2 = qjx * u1 - qjy * u0;
        float mq0 = fmaxf(mx0 * mx0, mn0 * mn0);
        float mq1 = fmaxf(mx1 * mx1, mn1 * mn1);
        float mq2 = fmaxf(mx2 * mx2, mn2 * mn2);

        if (l == 0) {   // all values wave-reduced; lane 0 folds into LDS pool
            atomicMax(&pool_lds[ 0], enc_f32(qjx));
            atomicMax(&pool_lds[ 1], enc_f32(qjy));
            atomicMax(&pool_lds[ 2], enc_f32(qjz));
            atomicMax(&pool_lds[ 3], enc_f32(mu0));
            atomicMax(&pool_lds[ 4], enc_f32(mu1));
            atomicMax(&pool_lds[ 5], enc_f32(mu2));
            atomicMax(&pool_lds[ 6], enc_f32(mx0));
            atomicMax(&pool_lds[ 7], enc_f32(mx1));
            atomicMax(&pool_lds[ 8], enc_f32(mx2));
            atomicMax(&pool_lds[ 9], enc_f32(mn0));
            atomicMax(&pool_lds[10], enc_f32(mn1));
            atomicMax(&pool_lds[11], enc_f32(mn2));
            atomicMax(&pool_lds[12], enc_f32(st0));
            atomicMax(&pool_lds[13], enc_f32(st1));
            atomicMax(&pool_lds[14], enc_f32(st2));
            atomicMax(&pool_lds[15], enc_f32(qjx - mu0));
            atomicMax(&pool_lds[16], enc_f32(qjy - mu1));
            atomicMax(&pool_lds[17], enc_f32(qjz - mu2));
            atomicMax(&pool_lds[18], enc_f32(u0));
            atomicMax(&pool_lds[19], enc_f32(u1));
            atomicMax(&pool_lds[20], enc_f32(u2));
            atomicMax(&pool_lds[21], enc_f32(cr0));
            atomicMax(&pool_lds[22], enc_f32(cr1));
            atomicMax(&pool_lds[23], enc_f32(cr2));
            atomicMax(&pool_lds[24], enc_f32(mq0));
            atomicMax(&pool_lds[25], enc_f32(mq1));
            atomicMax(&pool_lds[26], enc_f32(mq2));
            atomicMax(&pool_lds[27], enc_f32(ex0));
            atomicMax(&pool_lds[28], enc_f32(ex1));
            atomicMax(&pool_lds[29], enc_f32(ex2));
        }
    }
    __syncthreads();

    if (tid < CH)
        atomicMax(pool + b * CH + tid, pool_lds[tid]);
#undef BSTEP
#undef SORT64
#undef CLEAN64
#undef SURV_LOAD
#undef RSUM
#undef RMAXW
#undef RMINW
}

__global__ void final_mm_kernel(const unsigned* __restrict__ pool,
                                const float* __restrict__ W,
                                const float* __restrict__ bias,
                                float* __restrict__ out) {
    int t = blockIdx.x * blockDim.x + threadIdx.x;
    if (t >= BATCH * 32) return;
    int bb = t >> 5, e = t & 31;
    float acc = bias[e];
#pragma unroll
    for (int c = 0; c < CH; ++c)
        acc += dec_f32(pool[bb * CH + c]) * W[e * CH + c];
    out[bb * 32 + e] = acc;
}

extern "C" void kernel_launch(void* const* d_in, const int* in_sizes, int n_in,
                              void* d_out, int out_size, void* d_ws, size_t ws_size,
                              hipStream_t stream) {
    const float* x    = (const float*)d_in[0];   // [16, 4096, 3] f32
    const float* W    = (const float*)d_in[1];   // [32, 30] f32
    const float* bias = (const float*)d_in[2];   // [32] f32
    float*       out  = (float*)d_out;           // [16, 32] f32
    unsigned*    pool = (unsigned*)d_ws;         // [16, 30] encoded f32

    hipLaunchKernelGGL(init_pool_kernel, dim3(1), dim3(512), 0, stream, pool);
    hipLaunchKernelGGL(knn_kernel, dim3(BATCH * (NPTS / QPB)), dim3(512),
                       0, stream, x, pool);
    hipLaunchKernelGGL(final_mm_kernel, dim3(1), dim3(512), 0, stream, pool, W, bias, out);
}

// Round 17
// 226.127 us; speedup vs baseline: 1.1964x; 1.1964x over previous
//
#include <hip/hip_runtime.h>

#pragma clang fp contract(off)

#define BATCH 16
#define NPTS  4096
#define KNN   32
#define CH    30
#define NW    8                 // waves per block = chunk count
#define CHUNK (NPTS / NW)       // 512 candidates per wave
#define FD    30                // FIFO capacity per (region,lane); slot FD = trash
#define FSTR  31                // u16 slots per lane column

#define INF_F __builtin_inff()

typedef __attribute__((ext_vector_type(2))) float f32x2;

__device__ __forceinline__ unsigned enc_f32(float f) {
    unsigned u = __float_as_uint(f);
    return (u & 0x80000000u) ? ~u : (u | 0x80000000u);
}
__device__ __forceinline__ float dec_f32(unsigned e) {
    unsigned u = (e & 0x80000000u) ? (e & 0x7FFFFFFFu) : ~e;
    return __uint_as_float(u);
}

__device__ __forceinline__ float med3f(float a, float b, float c) {
#if __has_builtin(__builtin_amdgcn_fmed3f)
    return __builtin_amdgcn_fmed3f(a, b, c);
#else
    float r;
    asm("v_med3_f32 %0, %1, %2, %3" : "=v"(r) : "v"(a), "v"(b), "v"(c));
    return r;
#endif
}

// Scalar difference-form squared distance (phase 3; the reference metric).
__device__ __forceinline__ float dist3d(float qx, float qy, float qz,
                                        float px, float py, float pz) {
    float r0 = px - qx, r1 = py - qy, r2 = pz - qz;
    return __builtin_fmaf(r0, r0, __builtin_fmaf(r1, r1, r2 * r2));
}

// Packed 2-CANDIDATE distance: query splats into both slots; per-slot
// operation sequence IDENTICAL to dist3d -> bit-identical per candidate.
__device__ __forceinline__ f32x2 dist2c(f32x2 qxx, f32x2 qyy, f32x2 qzz,
                                        f32x2 px, f32x2 py, f32x2 pz) {
    f32x2 r0 = px - qxx, r1 = py - qyy, r2 = pz - qzz;
    return __builtin_elementwise_fma(r0, r0,
           __builtin_elementwise_fma(r1, r1, r2 * r2));
}

__global__ void init_pool_kernel(unsigned* __restrict__ pool) {
    int i = blockIdx.x * blockDim.x + threadIdx.x;
    if (i < BATCH * CH) pool[i] = 0u;   // 0 is below every encoded finite float
}

// 512 thr = 8 waves. Lane l owns query (qg*64+l) for passes 1-2; wave w scans
// chunk [w*512, w*512+512) two candidates at a time (packed f32 VOP3P).
// Candidate stream is wave-uniform (readfirstlane -> scalar loads). Phase 3
// is wave-parallel per query — verbatim from the r13/r14 lineage.
__launch_bounds__(512, 8)
__global__ void knn_kernel(const float* __restrict__ x,
                           unsigned* __restrict__ pool) {
    __shared__ unsigned short fifo[NW * 64 * FSTR];   // 31744 B [r][lane][slot]
    __shared__ float scratch[CH * 64];                // 7680 B: t8 then feat
    __shared__ unsigned char cbs[NW * 64];            // 512 B survivor counts

    const int b   = blockIdx.x >> 6;
    const int qg  = blockIdx.x & 63;
    const int tid = threadIdx.x;
    const int w   = tid >> 6;                     // wave id = chunk id (0..7)
    const int l   = tid & 63;
    const int q   = qg * 64 + l;
    const float* __restrict__ xb = x + (size_t)b * NPTS * 3;

    const float qx = xb[q * 3 + 0], qy = xb[q * 3 + 1], qz = xb[q * 3 + 2];
    const f32x2 qxx = { qx, qx }, qyy = { qy, qy }, qzz = { qz, qz };

    // Wave-uniform chunk base, made provably scalar.
    const int wu = __builtin_amdgcn_readfirstlane(w);
    const float* __restrict__ cw = xb + (size_t)wu * (CHUNK * 3);

    // ---- Pass 1: top-4 of my chunk (named scalars, 2 candidates/iter).
    // Union of 8 chunk-top-4s = 32 distinct points => t_cap >= true d32.
    float B0 = INF_F, B1 = INF_F, B2 = INF_F, B3 = INF_F;
#define INSERT4(dv)                          \
    {                                        \
        B3 = med3f(B2, B3, (dv));            \
        B2 = med3f(B1, B2, (dv));            \
        B1 = med3f(B0, B1, (dv));            \
        B0 = fminf(B0, (dv));                \
    }
#pragma unroll 2
    for (int m2 = 0; m2 < CHUNK / 2; ++m2) {
        f32x2 px = { cw[6 * m2 + 0], cw[6 * m2 + 3] };
        f32x2 py = { cw[6 * m2 + 1], cw[6 * m2 + 4] };
        f32x2 pz = { cw[6 * m2 + 2], cw[6 * m2 + 5] };
        f32x2 dd = dist2c(qxx, qyy, qzz, px, py, pz);
        INSERT4(dd[0]);
        INSERT4(dd[1]);
    }
#undef INSERT4
    scratch[w * 64 + l] = B3;                 // t8 stash
    __syncthreads();
    float t_cap = scratch[l];
#pragma unroll
    for (int ww = 1; ww < NW; ++ww) t_cap = fmaxf(t_cap, scratch[ww * 64 + l]);

    // ---- Pass 2: branchless collect of global u16 indices with d <= t_cap.
    // Pushes in candidate order (2m before 2m+1) -> index order preserved.
    unsigned short* __restrict__ fl = fifo + (w * 64 + l) * FSTR;
    int cnt = 0;
#pragma unroll 2
    for (int m2 = 0; m2 < CHUNK / 2; ++m2) {
        f32x2 px = { cw[6 * m2 + 0], cw[6 * m2 + 3] };
        f32x2 py = { cw[6 * m2 + 1], cw[6 * m2 + 4] };
        f32x2 pz = { cw[6 * m2 + 2], cw[6 * m2 + 5] };
        f32x2 dd = dist2c(qxx, qyy, qzz, px, py, pz);
        int mb = wu * CHUNK + m2 * 2;
        { bool t = (dd[0] <= t_cap) && (cnt < FD); fl[t ? cnt : FD] = (unsigned short)(mb + 0); cnt += t; }
        { bool t = (dd[1] <= t_cap) && (cnt < FD); fl[t ? cnt : FD] = (unsigned short)(mb + 1); cnt += t; }
    }
    cbs[w * 64 + l] = (unsigned char)cnt;
    __syncthreads();

    // ---- Phase 3: wave w processes queries j = w*8 .. w*8+7. ----
    float* __restrict__ feat = scratch;       // t8 fully consumed above

#define BSTEP(V, K, J)                                            \
    {                                                             \
        float pv_ = __shfl_xor((V), (J), 64);                     \
        bool km_ = (((l & (K)) == 0) == ((l & (J)) == 0));        \
        (V) = km_ ? fminf((V), pv_) : fmaxf((V), pv_);            \
    }
#define SORT64(V)                                                      \
    BSTEP(V, 2, 1)                                                     \
    BSTEP(V, 4, 2)  BSTEP(V, 4, 1)                                     \
    BSTEP(V, 8, 4)  BSTEP(V, 8, 2)  BSTEP(V, 8, 1)                     \
    BSTEP(V, 16, 8) BSTEP(V, 16, 4) BSTEP(V, 16, 2) BSTEP(V, 16, 1)    \
    BSTEP(V, 32,16) BSTEP(V, 32, 8) BSTEP(V, 32, 4) BSTEP(V, 32, 2) BSTEP(V, 32, 1) \
    BSTEP(V, 64,32) BSTEP(V, 64,16) BSTEP(V, 64, 8) BSTEP(V, 64, 4) BSTEP(V, 64, 2) BSTEP(V, 64, 1)
#define CLEAN64(V) \
    BSTEP(V, 64,32) BSTEP(V, 64,16) BSTEP(V, 64, 8) BSTEP(V, 64, 4) BSTEP(V, 64, 2) BSTEP(V, 64, 1)

#define SURV_LOAD(OFF, DOR, PX, PY, PZ)                                       \
    {                                                                         \
        int o_ = (OFF) + l;                                                   \
        int base_ = 0;                                                        \
        base_ = (o_ >= P1) ? P1 : base_;  base_ = (o_ >= P2) ? P2 : base_;    \
        base_ = (o_ >= P3) ? P3 : base_;  base_ = (o_ >= P4) ? P4 : base_;    \
        base_ = (o_ >= P5) ? P5 : base_;  base_ = (o_ >= P6) ? P6 : base_;    \
        base_ = (o_ >= P7) ? P7 : base_;                                      \
        int reg_ = (o_>=P1)+(o_>=P2)+(o_>=P3)+(o_>=P4)+(o_>=P5)+(o_>=P6)+(o_>=P7); \
        int s_ = o_ - base_;  s_ = (s_ > FD) ? FD : s_;                       \
        int idx_ = (int)fifo[(reg_ * 64 + j) * FSTR + s_];                    \
        const float* pp_ = xb + 3 * idx_;                                     \
        (PX) = pp_[0]; (PY) = pp_[1]; (PZ) = pp_[2];                          \
        float d_ = dist3d(qjx, qjy, qjz, (PX), (PY), (PZ));                   \
        (DOR) = (o_ < S) ? d_ : INF_F;                                        \
    }

#define RSUM(V) { _Pragma("unroll") for (int o_ = 32; o_ >= 1; o_ >>= 1) (V) += __shfl_xor((V), o_, 64); }
#define RMAXW(V) { _Pragma("unroll") for (int o_ = 32; o_ >= 1; o_ >>= 1) (V) = fmaxf((V), __shfl_xor((V), o_, 64)); }
#define RMINW(V) { _Pragma("unroll") for (int o_ = 32; o_ >= 1; o_ >>= 1) (V) = fminf((V), __shfl_xor((V), o_, 64)); }

#pragma unroll 1
    for (int jj = 0; jj < 8; ++jj) {
        const int j  = w * 8 + jj;
        const int qj = qg * 64 + j;
        const float qjx = xb[qj * 3 + 0], qjy = xb[qj * 3 + 1], qjz = xb[qj * 3 + 2];

        const int c0 = cbs[0 * 64 + j], c1 = cbs[1 * 64 + j],
                  c2 = cbs[2 * 64 + j], c3 = cbs[3 * 64 + j],
                  c4 = cbs[4 * 64 + j], c5 = cbs[5 * 64 + j],
                  c6 = cbs[6 * 64 + j], c7 = cbs[7 * 64 + j];
        const int P1 = c0,      P2 = P1 + c1, P3 = P2 + c2, P4 = P3 + c3,
                  P5 = P4 + c4, P6 = P5 + c5, P7 = P6 + c6, S  = P7 + c7;

        float px1, py1, pz1, dor1;
        SURV_LOAD(0, dor1, px1, py1, pz1);
        float v = dor1;
        SORT64(v)

        float thr;
        float px2 = 0.f, py2 = 0.f, pz2 = 0.f, dor2 = INF_F;
        const bool two = (S > 64);                 // wave-uniform
        if (two) {
            SURV_LOAD(64, dor2, px2, py2, pz2);
            float v2 = dor2;
            SORT64(v2)
            float rb = __shfl(v2, 63 - l, 64);     // reversed batch-2
            float lo = fminf(v, rb);               // bitonic lowest-64
            CLEAN64(lo)
            thr = __shfl(lo, 31, 64);
        } else {
            thr = __shfl(v, 31, 64);               // 32nd smallest
        }

        const unsigned long long blt = (l == 0) ? 0ull : (~0ull >> (64 - l));
        unsigned long long meq1 = __ballot(dor1 == thr);
        int clt = __popcll(__ballot(dor1 < thr));
        int neq1 = __popcll(meq1);
        int rank1 = __popcll(meq1 & blt);
        int rank2 = 0;
        if (two) {
            unsigned long long meq2 = __ballot(dor2 == thr);
            clt += __popcll(__ballot(dor2 < thr));
            rank2 = neq1 + __popcll(meq2 & blt);
        }
        const int need = KNN - clt;
        const bool take1 = (dor1 < thr) || ((dor1 == thr) && (rank1 < need));
        const bool take2 = two && ((dor2 < thr) || ((dor2 == thr) && (rank2 < need)));

        float r10 = px1 - qjx, r11 = py1 - qjy, r12 = pz1 - qjz;
        float r20 = px2 - qjx, r21 = py2 - qjy, r22 = pz2 - qjz;
        float s0 = (take1 ? r10 : 0.f) + (take2 ? r20 : 0.f);
        float s1 = (take1 ? r11 : 0.f) + (take2 ? r21 : 0.f);
        float s2 = (take1 ? r12 : 0.f) + (take2 ? r22 : 0.f);
        float ss0 = (take1 ? r10 * r10 : 0.f) + (take2 ? r20 * r20 : 0.f);
        float ss1 = (take1 ? r11 * r11 : 0.f) + (take2 ? r21 * r21 : 0.f);
        float ss2 = (take1 ? r12 * r12 : 0.f) + (take2 ? r22 * r22 : 0.f);
        float mx0 = fmaxf(take1 ? r10 : -INF_F, take2 ? r20 : -INF_F);
        float mx1 = fmaxf(take1 ? r11 : -INF_F, take2 ? r21 : -INF_F);
        float mx2 = fmaxf(take1 ? r12 : -INF_F, take2 ? r22 : -INF_F);
        float mn0 = fminf(take1 ? r10 : INF_F, take2 ? r20 : INF_F);
        float mn1 = fminf(take1 ? r11 : INF_F, take2 ? r21 : INF_F);
        float mn2 = fminf(take1 ? r12 : INF_F, take2 ? r22 : INF_F);

        RSUM(s0)  RSUM(s1)  RSUM(s2)
        RSUM(ss0) RSUM(ss1) RSUM(ss2)
        RMAXW(mx0) RMAXW(mx1) RMAXW(mx2)
        RMINW(mn0) RMINW(mn1) RMINW(mn2)

        const float invk = 1.0f / (float)KNN;
        float mu0 = s0 * invk, mu1 = s1 * invk, mu2 = s2 * invk;
        float ex0 = ss0 * invk, ex1 = ss1 * invk, ex2 = ss2 * invk;
        float st0 = sqrtf(fmaxf(ex0 - mu0 * mu0, 0.f));
        float st1 = sqrtf(fmaxf(ex1 - mu1 * mu1, 0.f));
        float st2 = sqrtf(fmaxf(ex2 - mu2 * mu2, 0.f));
        float nrm = sqrtf(mu0 * mu0 + mu1 * mu1 + mu2 * mu2) + 1e-8f;
        float u0 = mu0 / nrm, u1 = mu1 / nrm, u2 = mu2 / nrm;
        float cr0 = qjy * u2 - qjz * u1;
        float cr1 = qjz * u0 - qjx * u2;
        float cr2 = qjx * u1 - qjy * u0;
        float mq0 = fmaxf(mx0 * mx0, mn0 * mn0);
        float mq1 = fmaxf(mx1 * mx1, mn1 * mn1);
        float mq2 = fmaxf(mx2 * mx2, mn2 * mn2);

        if (l == 0) {
            feat[ 0 * 64 + j] = qjx;        feat[ 1 * 64 + j] = qjy;
            feat[ 2 * 64 + j] = qjz;        feat[ 3 * 64 + j] = mu0;
            feat[ 4 * 64 + j] = mu1;        feat[ 5 * 64 + j] = mu2;
            feat[ 6 * 64 + j] = mx0;        feat[ 7 * 64 + j] = mx1;
            feat[ 8 * 64 + j] = mx2;        feat[ 9 * 64 + j] = mn0;
            feat[10 * 64 + j] = mn1;        feat[11 * 64 + j] = mn2;
            feat[12 * 64 + j] = st0;        feat[13 * 64 + j] = st1;
            feat[14 * 64 + j] = st2;        feat[15 * 64 + j] = qjx - mu0;
            feat[16 * 64 + j] = qjy - mu1;  feat[17 * 64 + j] = qjz - mu2;
            feat[18 * 64 + j] = u0;         feat[19 * 64 + j] = u1;
            feat[20 * 64 + j] = u2;         feat[21 * 64 + j] = cr0;
            feat[22 * 64 + j] = cr1;        feat[23 * 64 + j] = cr2;
            feat[24 * 64 + j] = mq0;        feat[25 * 64 + j] = mq1;
            feat[26 * 64 + j] = mq2;        feat[27 * 64 + j] = ex0;
            feat[28 * 64 + j] = ex1;        feat[29 * 64 + j] = ex2;
        }
    }
    __syncthreads();

    // ---- Block max-pool over 64 queries, one atomic per channel. ----
    if (w == 0) {
        for (int c = 0; c < CH; ++c) {
            float v_ = feat[c * 64 + l];
            RMAXW(v_)
            if (l == 0) atomicMax(pool + b * CH + c, enc_f32(v_));
        }
    }
#undef BSTEP
#undef SORT64
#undef CLEAN64
#undef SURV_LOAD
#undef RSUM
#undef RMAXW
#undef RMINW
}

__global__ void final_mm_kernel(const unsigned* __restrict__ pool,
                                const float* __restrict__ W,
                                const float* __restrict__ bias,
                                float* __restrict__ out) {
    int t = blockIdx.x * blockDim.x + threadIdx.x;
    if (t >= BATCH * 32) return;
    int bb = t >> 5, e = t & 31;
    float acc = bias[e];
#pragma unroll
    for (int c = 0; c < CH; ++c)
        acc += dec_f32(pool[bb * CH + c]) * W[e * CH + c];
    out[bb * 32 + e] = acc;
}

extern "C" void kernel_launch(void* const* d_in, const int* in_sizes, int n_in,
                              void* d_out, int out_size, void* d_ws, size_t ws_size,
                              hipStream_t stream) {
    const float* x    = (const float*)d_in[0];   // [16, 4096, 3] f32
    const float* W    = (const float*)d_in[1];   // [32, 30] f32
    const float* bias = (const float*)d_in[2];   // [32] f32
    float*       out  = (float*)d_out;           // [16, 32] f32
    unsigned*    pool = (unsigned*)d_ws;         // [16, 30] encoded f32

    hipLaunchKernelGGL(init_pool_kernel, dim3(1), dim3(512), 0, stream, pool);
    hipLaunchKernelGGL(knn_kernel, dim3(BATCH * (NPTS / 64)), dim3(512),
                       0, stream, x, pool);
    hipLaunchKernelGGL(final_mm_kernel, dim3(1), dim3(512), 0, stream, pool, W, bias, out);
}

// Round 18
// 203.428 us; speedup vs baseline: 1.3298x; 1.1116x over previous
//
#include <hip/hip_runtime.h>

#pragma clang fp contract(off)

#define BATCH 16
#define NPTS  4096
#define KNN   32
#define CH    30
#define NW    8                 // waves per block = chunk count
#define CHUNK (NPTS / NW)       // 512 candidates per wave
#define FD    30                // FIFO capacity per (region,lane); slot FD = trash
#define FSTR  31                // u16 slots per lane column

#define INF_F __builtin_inff()

__device__ __forceinline__ unsigned enc_f32(float f) {
    unsigned u = __float_as_uint(f);
    return (u & 0x80000000u) ? ~u : (u | 0x80000000u);
}
__device__ __forceinline__ float dec_f32(unsigned e) {
    unsigned u = (e & 0x80000000u) ? (e & 0x7FFFFFFFu) : ~e;
    return __uint_as_float(u);
}

__device__ __forceinline__ float med3f(float a, float b, float c) {
#if __has_builtin(__builtin_amdgcn_fmed3f)
    return __builtin_amdgcn_fmed3f(a, b, c);
#else
    float r;
    asm("v_med3_f32 %0, %1, %2, %3" : "=v"(r) : "v"(a), "v"(b), "v"(c));
    return r;
#endif
}

// Difference-form squared distance, fma-fixed: ONE formula in EVERY pass ->
// bit-identical d everywhere (contract off).
__device__ __forceinline__ float dist3d(float qx, float qy, float qz,
                                        float px, float py, float pz) {
    float r0 = px - qx, r1 = py - qy, r2 = pz - qz;
    return __builtin_fmaf(r0, r0, __builtin_fmaf(r1, r1, r2 * r2));
}

__global__ void init_pool_kernel(unsigned* __restrict__ pool) {
    int i = blockIdx.x * blockDim.x + threadIdx.x;
    if (i < BATCH * CH) pool[i] = 0u;   // 0 is below every encoded finite float
}

// 512 thr = 8 waves. Lane l owns query (qg*64+l) for passes 1-2; wave w scans
// chunk [w*512, w*512+512). Candidate stream is WAVE-UNIFORM: readfirstlane
// forces the compiler to scalarize it (s_load -> SGPRs, scalar pipe), leaving
// only ~10-12 VALU per candidate. Phase 3 is wave-parallel per query.
__launch_bounds__(512, 8)
__global__ void knn_kernel(const float* __restrict__ x,
                           unsigned* __restrict__ pool) {
    __shared__ unsigned short fifo[NW * 64 * FSTR];   // 31744 B [r][lane][slot]
    __shared__ float scratch[CH * 64];                // 7680 B: t8 then feat
    __shared__ unsigned char cbs[NW * 64];            // 512 B survivor counts

    const int b   = blockIdx.x >> 6;
    const int qg  = blockIdx.x & 63;
    const int tid = threadIdx.x;
    const int w   = tid >> 6;                     // wave id = chunk id (0..7)
    const int l   = tid & 63;
    const int q   = qg * 64 + l;
    const float* __restrict__ xb = x + (size_t)b * NPTS * 3;

    const float qx = xb[q * 3 + 0], qy = xb[q * 3 + 1], qz = xb[q * 3 + 2];

    // Wave-uniform chunk base, made provably scalar.
    const int wu = __builtin_amdgcn_readfirstlane(w);
    const float* __restrict__ cw = xb + (size_t)wu * (CHUNK * 3);

    // ---- Pass 1: top-4 of my chunk (named scalars). Union 8x4 = 32 distinct
    // points => t_cap = max of chunk-4ths >= true 32nd distance.
    float B0 = INF_F, B1 = INF_F, B2 = INF_F, B3 = INF_F;
#define INSERT4(dv)                          \
    {                                        \
        B3 = med3f(B2, B3, (dv));            \
        B2 = med3f(B1, B2, (dv));            \
        B1 = med3f(B0, B1, (dv));            \
        B0 = fminf(B0, (dv));                \
    }
#pragma unroll 4
    for (int m = 0; m < CHUNK; ++m) {
        float px = cw[3 * m + 0], py = cw[3 * m + 1], pz = cw[3 * m + 2];
        float d = dist3d(qx, qy, qz, px, py, pz);
        INSERT4(d);
    }
#undef INSERT4
    scratch[w * 64 + l] = B3;                 // t8 stash
    __syncthreads();
    float t_cap = scratch[l];
#pragma unroll
    for (int ww = 1; ww < NW; ++ww) t_cap = fmaxf(t_cap, scratch[ww * 64 + l]);

    // ---- Pass 2: branchless collect of global u16 indices with d <= t_cap.
    unsigned short* __restrict__ fl = fifo + (w * 64 + l) * FSTR;
    int cnt = 0;
#pragma unroll 4
    for (int m = 0; m < CHUNK; ++m) {
        float px = cw[3 * m + 0], py = cw[3 * m + 1], pz = cw[3 * m + 2];
        float d = dist3d(qx, qy, qz, px, py, pz);
        bool t = (d <= t_cap) && (cnt < FD);
        fl[t ? cnt : FD] = (unsigned short)(wu * CHUNK + m);
        cnt += t;
    }
    cbs[w * 64 + l] = (unsigned char)cnt;
    __syncthreads();

    // ---- Phase 3: wave w processes queries j = w*8 .. w*8+7. ----
    float* __restrict__ feat = scratch;       // t8 fully consumed above

#define BSTEP(V, K, J)                                            \
    {                                                             \
        float pv_ = __shfl_xor((V), (J), 64);                     \
        bool km_ = (((l & (K)) == 0) == ((l & (J)) == 0));        \
        (V) = km_ ? fminf((V), pv_) : fmaxf((V), pv_);            \
    }
#define SORT64(V)                                                      \
    BSTEP(V, 2, 1)                                                     \
    BSTEP(V, 4, 2)  BSTEP(V, 4, 1)                                     \
    BSTEP(V, 8, 4)  BSTEP(V, 8, 2)  BSTEP(V, 8, 1)                     \
    BSTEP(V, 16, 8) BSTEP(V, 16, 4) BSTEP(V, 16, 2) BSTEP(V, 16, 1)    \
    BSTEP(V, 32,16) BSTEP(V, 32, 8) BSTEP(V, 32, 4) BSTEP(V, 32, 2) BSTEP(V, 32, 1) \
    BSTEP(V, 64,32) BSTEP(V, 64,16) BSTEP(V, 64, 8) BSTEP(V, 64, 4) BSTEP(V, 64, 2) BSTEP(V, 64, 1)
#define CLEAN64(V) \
    BSTEP(V, 64,32) BSTEP(V, 64,16) BSTEP(V, 64, 8) BSTEP(V, 64, 4) BSTEP(V, 64, 2) BSTEP(V, 64, 1)

#define SURV_LOAD(OFF, DOR, PX, PY, PZ)                                       \
    {                                                                         \
        int o_ = (OFF) + l;                                                   \
        int base_ = 0;                                                        \
        base_ = (o_ >= P1) ? P1 : base_;  base_ = (o_ >= P2) ? P2 : base_;    \
        base_ = (o_ >= P3) ? P3 : base_;  base_ = (o_ >= P4) ? P4 : base_;    \
        base_ = (o_ >= P5) ? P5 : base_;  base_ = (o_ >= P6) ? P6 : base_;    \
        base_ = (o_ >= P7) ? P7 : base_;                                      \
        int reg_ = (o_>=P1)+(o_>=P2)+(o_>=P3)+(o_>=P4)+(o_>=P5)+(o_>=P6)+(o_>=P7); \
        int s_ = o_ - base_;  s_ = (s_ > FD) ? FD : s_;                       \
        int idx_ = (int)fifo[(reg_ * 64 + j) * FSTR + s_];                    \
        const float* pp_ = xb + 3 * idx_;                                     \
        (PX) = pp_[0]; (PY) = pp_[1]; (PZ) = pp_[2];                          \
        float d_ = dist3d(qjx, qjy, qjz, (PX), (PY), (PZ));                   \
        (DOR) = (o_ < S) ? d_ : INF_F;                                        \
    }

#define RSUM(V) { _Pragma("unroll") for (int o_ = 32; o_ >= 1; o_ >>= 1) (V) += __shfl_xor((V), o_, 64); }
#define RMAXW(V) { _Pragma("unroll") for (int o_ = 32; o_ >= 1; o_ >>= 1) (V) = fmaxf((V), __shfl_xor((V), o_, 64)); }
#define RMINW(V) { _Pragma("unroll") for (int o_ = 32; o_ >= 1; o_ >>= 1) (V) = fminf((V), __shfl_xor((V), o_, 64)); }

#pragma unroll 1
    for (int jj = 0; jj < 8; ++jj) {
        const int j  = w * 8 + jj;
        const int qj = qg * 64 + j;
        const float qjx = xb[qj * 3 + 0], qjy = xb[qj * 3 + 1], qjz = xb[qj * 3 + 2];

        const int c0 = cbs[0 * 64 + j], c1 = cbs[1 * 64 + j],
                  c2 = cbs[2 * 64 + j], c3 = cbs[3 * 64 + j],
                  c4 = cbs[4 * 64 + j], c5 = cbs[5 * 64 + j],
                  c6 = cbs[6 * 64 + j], c7 = cbs[7 * 64 + j];
        const int P1 = c0,      P2 = P1 + c1, P3 = P2 + c2, P4 = P3 + c3,
                  P5 = P4 + c4, P6 = P5 + c5, P7 = P6 + c6, S  = P7 + c7;

        float px1, py1, pz1, dor1;
        SURV_LOAD(0, dor1, px1, py1, pz1);
        float v = dor1;
        SORT64(v)

        float thr;
        float px2 = 0.f, py2 = 0.f, pz2 = 0.f, dor2 = INF_F;
        const bool two = (S > 64);                 // wave-uniform
        if (two) {
            SURV_LOAD(64, dor2, px2, py2, pz2);
            float v2 = dor2;
            SORT64(v2)
            float rb = __shfl(v2, 63 - l, 64);     // reversed batch-2
            float lo = fminf(v, rb);               // bitonic lowest-64
            CLEAN64(lo)
            thr = __shfl(lo, 31, 64);
        } else {
            thr = __shfl(v, 31, 64);               // 32nd smallest
        }

        const unsigned long long blt = (l == 0) ? 0ull : (~0ull >> (64 - l));
        unsigned long long meq1 = __ballot(dor1 == thr);
        int clt = __popcll(__ballot(dor1 < thr));
        int neq1 = __popcll(meq1);
        int rank1 = __popcll(meq1 & blt);
        int rank2 = 0;
        if (two) {
            unsigned long long meq2 = __ballot(dor2 == thr);
            clt += __popcll(__ballot(dor2 < thr));
            rank2 = neq1 + __popcll(meq2 & blt);
        }
        const int need = KNN - clt;
        const bool take1 = (dor1 < thr) || ((dor1 == thr) && (rank1 < need));
        const bool take2 = two && ((dor2 < thr) || ((dor2 == thr) && (rank2 < need)));

        float r10 = px1 - qjx, r11 = py1 - qjy, r12 = pz1 - qjz;
        float r20 = px2 - qjx, r21 = py2 - qjy, r22 = pz2 - qjz;
        float s0 = (take1 ? r10 : 0.f) + (take2 ? r20 : 0.f);
        float s1 = (take1 ? r11 : 0.f) + (take2 ? r21 : 0.f);
        float s2 = (take1 ? r12 : 0.f) + (take2 ? r22 : 0.f);
        float ss0 = (take1 ? r10 * r10 : 0.f) + (take2 ? r20 * r20 : 0.f);
        float ss1 = (take1 ? r11 * r11 : 0.f) + (take2 ? r21 * r21 : 0.f);
        float ss2 = (take1 ? r12 * r12 : 0.f) + (take2 ? r22 * r22 : 0.f);
        float mx0 = fmaxf(take1 ? r10 : -INF_F, take2 ? r20 : -INF_F);
        float mx1 = fmaxf(take1 ? r11 : -INF_F, take2 ? r21 : -INF_F);
        float mx2 = fmaxf(take1 ? r12 : -INF_F, take2 ? r22 : -INF_F);
        float mn0 = fminf(take1 ? r10 : INF_F, take2 ? r20 : INF_F);
        float mn1 = fminf(take1 ? r11 : INF_F, take2 ? r21 : INF_F);
        float mn2 = fminf(take1 ? r12 : INF_F, take2 ? r22 : INF_F);

        RSUM(s0)  RSUM(s1)  RSUM(s2)
        RSUM(ss0) RSUM(ss1) RSUM(ss2)
        RMAXW(mx0) RMAXW(mx1) RMAXW(mx2)
        RMINW(mn0) RMINW(mn1) RMINW(mn2)

        const float invk = 1.0f / (float)KNN;
        float mu0 = s0 * invk, mu1 = s1 * invk, mu2 = s2 * invk;
        float ex0 = ss0 * invk, ex1 = ss1 * invk, ex2 = ss2 * invk;
        float st0 = sqrtf(fmaxf(ex0 - mu0 * mu0, 0.f));
        float st1 = sqrtf(fmaxf(ex1 - mu1 * mu1, 0.f));
        float st2 = sqrtf(fmaxf(ex2 - mu2 * mu2, 0.f));
        float nrm = sqrtf(mu0 * mu0 + mu1 * mu1 + mu2 * mu2) + 1e-8f;
        float u0 = mu0 / nrm, u1 = mu1 / nrm, u2 = mu2 / nrm;
        float cr0 = qjy * u2 - qjz * u1;
        float cr1 = qjz * u0 - qjx * u2;
        float cr2 = qjx * u1 - qjy * u0;
        float mq0 = fmaxf(mx0 * mx0, mn0 * mn0);
        float mq1 = fmaxf(mx1 * mx1, mn1 * mn1);
        float mq2 = fmaxf(mx2 * mx2, mn2 * mn2);

        if (l == 0) {
            feat[ 0 * 64 + j] = qjx;        feat[ 1 * 64 + j] = qjy;
            feat[ 2 * 64 + j] = qjz;        feat[ 3 * 64 + j] = mu0;
            feat[ 4 * 64 + j] = mu1;        feat[ 5 * 64 + j] = mu2;
            feat[ 6 * 64 + j] = mx0;        feat[ 7 * 64 + j] = mx1;
            feat[ 8 * 64 + j] = mx2;        feat[ 9 * 64 + j] = mn0;
            feat[10 * 64 + j] = mn1;        feat[11 * 64 + j] = mn2;
            feat[12 * 64 + j] = st0;        feat[13 * 64 + j] = st1;
            feat[14 * 64 + j] = st2;        feat[15 * 64 + j] = qjx - mu0;
            feat[16 * 64 + j] = qjy - mu1;  feat[17 * 64 + j] = qjz - mu2;
            feat[18 * 64 + j] = u0;         feat[19 * 64 + j] = u1;
            feat[20 * 64 + j] = u2;         feat[21 * 64 + j] = cr0;
            feat[22 * 64 + j] = cr1;        feat[23 * 64 + j] = cr2;
            feat[24 * 64 + j] = mq0;        feat[25 * 64 + j] = mq1;
            feat[26 * 64 + j] = mq2;        feat[27 * 64 + j] = ex0;
            feat[28 * 64 + j] = ex1;        feat[29 * 64 + j] = ex2;
        }
    }
    __syncthreads();

    // ---- Block max-pool over 64 queries, one atomic per channel. ----
    if (w == 0) {
        for (int c = 0; c < CH; ++c) {
            float v_ = feat[c * 64 + l];
            RMAXW(v_)
            if (l == 0) atomicMax(pool + b * CH + c, enc_f32(v_));
        }
    }
#undef BSTEP
#undef SORT64
#undef CLEAN64
#undef SURV_LOAD
#undef RSUM
#undef RMAXW
#undef RMINW
}

__global__ void final_mm_kernel(const unsigned* __restrict__ pool,
                                const float* __restrict__ W,
                                const float* __restrict__ bias,
                                float* __restrict__ out) {
    int t = blockIdx.x * blockDim.x + threadIdx.x;
    if (t >= BATCH * 32) return;
    int bb = t >> 5, e = t & 31;
    float acc = bias[e];
#pragma unroll
    for (int c = 0; c < CH; ++c)
        acc += dec_f32(pool[bb * CH + c]) * W[e * CH + c];
    out[bb * 32 + e] = acc;
}

extern "C" void kernel_launch(void* const* d_in, const int* in_sizes, int n_in,
                              void* d_out, int out_size, void* d_ws, size_t ws_size,
                              hipStream_t stream) {
    const float* x    = (const float*)d_in[0];   // [16, 4096, 3] f32
    const float* W    = (const float*)d_in[1];   // [32, 30] f32
    const float* bias = (const float*)d_in[2];   // [32] f32
    float*       out  = (float*)d_out;           // [16, 32] f32
    unsigned*    pool = (unsigned*)d_ws;         // [16, 30] encoded f32

    hipLaunchKernelGGL(init_pool_kernel, dim3(1), dim3(512), 0, stream, pool);
    hipLaunchKernelGGL(knn_kernel, dim3(BATCH * (NPTS / 64)), dim3(512),
                       0, stream, x, pool);
    hipLaunchKernelGGL(final_mm_kernel, dim3(1), dim3(512), 0, stream, pool, W, bias, out);
}